// Round 11
// baseline (775.987 us; speedup 1.0000x reference)
//
#include <hip/hip_runtime.h>
#include <hip/hip_bf16.h>
#include <cstdint>
#include <math.h>

// Problem constants: B=2,S=2048,E=2048,H=16,KH=4,G=4,D=128,F=8192, M=B*S=4096
typedef unsigned short u16;
using f32x4   = __attribute__((ext_vector_type(4))) float;
using short8  = __attribute__((ext_vector_type(8))) short;
using short4v = __attribute__((ext_vector_type(4))) short;

#define DEV static __device__ __forceinline__

DEV u16 f2bf(float f) {  // RNE f32 -> bf16
  union { float f; unsigned u; } v; v.f = f;
  unsigned r = v.u + 0x7fffu + ((v.u >> 16) & 1u);
  return (u16)(r >> 16);
}

DEV f32x4 mfma_bf16(short8 a, short8 b, f32x4 c) {
  return __builtin_amdgcn_mfma_f32_16x16x32_bf16(a, b, c, 0, 0, 0);
}

DEV void gload16(const void* g, void* l) {  // async global->LDS, 16B/lane, LDS base wave-uniform
  __builtin_amdgcn_global_load_lds((const __attribute__((address_space(1))) void*)g,
                                   (__attribute__((address_space(3))) void*)l,
                                   16, 0, 0);
}

// ---------------- prep mega-kernel: LN1 + all 6 weight transposes ------------
__global__ __launch_bounds__(256) void prep_kernel(
    const float* __restrict__ x, const float* __restrict__ g,
    const float* __restrict__ bt, u16* __restrict__ x1,
    const float* __restrict__ wq, const float* __restrict__ wk,
    const float* __restrict__ wv, const float* __restrict__ wo,
    const float* __restrict__ wu, const float* __restrict__ wd,
    u16* __restrict__ wqT, u16* __restrict__ wkT, u16* __restrict__ wvT,
    u16* __restrict__ woT, u16* __restrict__ wuT, u16* __restrict__ wdT)
{
  __shared__ float sm[32 * 33];
  int bid = blockIdx.x;
  const int t = threadIdx.x;

  if (bid < 4096) {                                    // ---- LayerNorm 1 ----
    const int lane = t & 63, w = t >> 6;
    const float* xr = x + (size_t)bid * 2048 + t * 8;
    float v[8];
    {
      const float4* p4 = (const float4*)xr;
      float4 a = p4[0], b = p4[1];
      v[0] = a.x; v[1] = a.y; v[2] = a.z; v[3] = a.w;
      v[4] = b.x; v[5] = b.y; v[6] = b.z; v[7] = b.w;
    }
    float s = 0.f;
#pragma unroll
    for (int j = 0; j < 8; j++) s += v[j];
#pragma unroll
    for (int m = 1; m < 64; m <<= 1) s += __shfl_xor(s, m);
    if (lane == 0) sm[w] = s;
    __syncthreads();
    const float mu = (sm[0] + sm[1] + sm[2] + sm[3]) * (1.f / 2048.f);
    float q = 0.f;
#pragma unroll
    for (int j = 0; j < 8; j++) { v[j] -= mu; q += v[j] * v[j]; }
#pragma unroll
    for (int m = 1; m < 64; m <<= 1) q += __shfl_xor(q, m);
    if (lane == 0) sm[4 + w] = q;
    __syncthreads();
    const float rstd = rsqrtf((sm[4] + sm[5] + sm[6] + sm[7]) * (1.f / 2048.f) + 1e-5f);
    const float4* g4 = (const float4*)(g + t * 8);
    const float4* b4 = (const float4*)(bt + t * 8);
    float4 ga = g4[0], gb = g4[1], ba = b4[0], bb = b4[1];
    float gg[8] = {ga.x, ga.y, ga.z, ga.w, gb.x, gb.y, gb.z, gb.w};
    float bbv[8] = {ba.x, ba.y, ba.z, ba.w, bb.x, bb.y, bb.z, bb.w};
    short8 o;
#pragma unroll
    for (int j = 0; j < 8; j++) o[j] = (short)f2bf(v[j] * rstd * gg[j] + bbv[j]);
    *(short8*)&x1[(size_t)bid * 2048 + t * 8] = o;
    return;
  }
  bid -= 4096;

  const float* in; u16* outp; int K, N, bx, by;
  if (bid < 4096)              { in = wq; outp = wqT; K = 2048; N = 2048; bx = bid & 63;  by = bid >> 6; }
  else if ((bid -= 4096) < 1024)  { in = wk; outp = wkT; K = 2048; N = 512;  bx = bid & 15;  by = bid >> 4; }
  else if ((bid -= 1024) < 1024)  { in = wv; outp = wvT; K = 2048; N = 512;  bx = bid & 15;  by = bid >> 4; }
  else if ((bid -= 1024) < 4096)  { in = wo; outp = woT; K = 2048; N = 2048; bx = bid & 63;  by = bid >> 6; }
  else if ((bid -= 4096) < 16384) { in = wu; outp = wuT; K = 2048; N = 8192; bx = bid & 255; by = bid >> 8; }
  else { bid -= 16384;            in = wd; outp = wdT; K = 8192; N = 2048; bx = bid & 63;  by = bid >> 6; }

  const int n0 = bx * 32, k0 = by * 32;
  {
    const int c = t & 31, r = t >> 5;               // r in 0..7
#pragma unroll
    for (int i = 0; i < 4; i++)
      sm[(r + i * 8) * 33 + c] = in[(size_t)(k0 + r + i * 8) * N + n0 + c];
  }
  __syncthreads();
  {
    const int c4 = (t & 7) * 4, r = t >> 3;         // r in 0..31
    short4v o;
#pragma unroll
    for (int j = 0; j < 4; j++) o[j] = (short)f2bf(sm[(c4 + j) * 33 + r]);
    *(short4v*)&outp[(size_t)(n0 + r) * K + k0 + c4] = o;
  }
}

// ---------------- LayerNorm (f32 in, bf16 out), one row (2048) per block ------
__global__ __launch_bounds__(256) void ln_kernel(
    const float* __restrict__ x, const float* __restrict__ g,
    const float* __restrict__ bt, u16* __restrict__ out)
{
  __shared__ float red1[4], red2[4];
  const int row = blockIdx.x;
  const int t = threadIdx.x;
  const int lane = t & 63, w = t >> 6;
  const float* xr = x + (size_t)row * 2048 + t * 8;
  float v[8];
  {
    const float4* p4 = (const float4*)xr;
    float4 a = p4[0], b = p4[1];
    v[0] = a.x; v[1] = a.y; v[2] = a.z; v[3] = a.w;
    v[4] = b.x; v[5] = b.y; v[6] = b.z; v[7] = b.w;
  }
  float s = 0.f;
#pragma unroll
  for (int j = 0; j < 8; j++) s += v[j];
#pragma unroll
  for (int m = 1; m < 64; m <<= 1) s += __shfl_xor(s, m);
  if (lane == 0) red1[w] = s;
  __syncthreads();
  const float mu = (red1[0] + red1[1] + red1[2] + red1[3]) * (1.f / 2048.f);
  float q = 0.f;
#pragma unroll
  for (int j = 0; j < 8; j++) { v[j] -= mu; q += v[j] * v[j]; }
#pragma unroll
  for (int m = 1; m < 64; m <<= 1) q += __shfl_xor(q, m);
  if (lane == 0) red2[w] = q;
  __syncthreads();
  const float rstd = rsqrtf((red2[0] + red2[1] + red2[2] + red2[3]) * (1.f / 2048.f) + 1e-5f);
  const float4* g4 = (const float4*)(g + t * 8);
  const float4* b4 = (const float4*)(bt + t * 8);
  float4 ga = g4[0], gb = g4[1], ba = b4[0], bb = b4[1];
  float gg[8] = {ga.x, ga.y, ga.z, ga.w, gb.x, gb.y, gb.z, gb.w};
  float bbv[8] = {ba.x, ba.y, ba.z, ba.w, bb.x, bb.y, bb.z, bb.w};
  short8 o;
#pragma unroll
  for (int j = 0; j < 8; j++) o[j] = (short)f2bf(v[j] * rstd * gg[j] + bbv[j]);
  *(short8*)&out[(size_t)row * 2048 + t * 8] = o;
}

// ---------------- gemm_sb: single-buffered m97 structure (QKV, O) ------------
// MODE: 3=O(bias+resid,f32) 6=QKV fused
template<int MODE, int N, int K, int STRIPE_N>
__global__ void __launch_bounds__(256) gemm_sb(
    const u16* __restrict__ A, const u16* __restrict__ Bt,
    const float* __restrict__ b0, const float* __restrict__ b1,
    const float* __restrict__ b2, const float* __restrict__ resid,
    u16* __restrict__ o0, u16* __restrict__ o1, u16* __restrict__ o2,
    float* __restrict__ of)
{
  __shared__ u16 As[128 * 64];
  __shared__ u16 Bs[128 * 64];
  constexpr int TN = N / 128;

  const int bid = blockIdx.x;
  const int xcd = bid & 7, wl = bid >> 3;
  int m0, n0;
  if constexpr (STRIPE_N) {
    constexpr int NSTR = TN / 8;
    n0 = (xcd * NSTR + (wl % NSTR)) * 128;
    m0 = (wl / NSTR) * 128;
  } else {
    m0 = (xcd * 4 + (wl & 3)) * 128;
    n0 = (wl >> 2) * 128;
  }
  const int tid = threadIdx.x;
  const int lane = tid & 63, w = tid >> 6;
  const int wm = w >> 1, wn = w & 1;
  const int z = lane >> 4, l15 = lane & 15;

  f32x4 acc[4][4];
#pragma unroll
  for (int m = 0; m < 4; m++)
#pragma unroll
    for (int n = 0; n < 4; n++)
#pragma unroll
      for (int i = 0; i < 4; i++) acc[m][n][i] = 0.f;

  for (int k0 = 0; k0 < K; k0 += 64) {
#pragma unroll
    for (int j = 0; j < 4; j++) {
      const int seg = w * 4 + j;
      const int c = seg * 64 + lane;
      const int r = c >> 3;
      const int cc = (c & 7) ^ (r & 7);
      gload16(A + (size_t)(m0 + r) * K + k0 + cc * 8, &As[seg * 512]);
    }
#pragma unroll
    for (int j = 0; j < 4; j++) {
      const int seg = w * 4 + j;
      const int c = seg * 64 + lane;
      const int r = c >> 3;
      const int cc = (c & 7) ^ (r & 7);
      gload16(Bt + (size_t)(n0 + r) * K + k0 + cc * 8, &Bs[seg * 512]);
    }
    asm volatile("s_waitcnt vmcnt(0)" ::: "memory");
    __syncthreads();

#pragma unroll
    for (int kk = 0; kk < 2; kk++) {
      short8 af[4], bfr[4];
#pragma unroll
      for (int m = 0; m < 4; m++) {
        const int row = wm * 64 + m * 16 + l15;
        const int off = row * 64 + ((kk * 32 + z * 8) ^ ((row & 7) << 3));
        af[m] = *(const short8*)&As[off];
      }
#pragma unroll
      for (int n = 0; n < 4; n++) {
        const int row = wn * 64 + n * 16 + l15;
        const int off = row * 64 + ((kk * 32 + z * 8) ^ ((row & 7) << 3));
        bfr[n] = *(const short8*)&Bs[off];
      }
      __builtin_amdgcn_s_setprio(1);
#pragma unroll
      for (int m = 0; m < 4; m++)
#pragma unroll
        for (int n = 0; n < 4; n++)
          acc[m][n] = mfma_bf16(af[m], bfr[n], acc[m][n]);
      __builtin_amdgcn_s_setprio(0);
    }
    __syncthreads();
  }

#pragma unroll
  for (int m = 0; m < 4; m++) {
    const int row0 = m0 + wm * 64 + m * 16 + z * 4;
#pragma unroll
    for (int n = 0; n < 4; n++) {
      const int col = n0 + wn * 64 + n * 16 + l15;
      f32x4 v = acc[m][n];
      if constexpr (MODE == 6) {
        if (col < 2048) {
          const float bb = b0[col];
#pragma unroll
          for (int i = 0; i < 4; i++)
            o0[(size_t)(row0 + i) * 2048 + col] = f2bf((v[i] + bb) * 0.08838834764831845f);
        } else if (col < 2560) {
          const int ck = col - 2048;
          const float bb = b1[ck];
#pragma unroll
          for (int i = 0; i < 4; i++)
            o1[(size_t)(row0 + i) * 512 + ck] = f2bf(v[i] + bb);
        } else {
          const int cc = col - 2560;
          const float bb = b2[cc];
          const int kh = cc >> 7, d = cc & 127;
          const int bidx = row0 >> 11, sidx = row0 & 2047;
          u16* vrow = &o2[((size_t)(bidx * 4 + kh) * 128 + d) * 2048 + sidx];
          short4v pq;
#pragma unroll
          for (int i = 0; i < 4; i++) pq[i] = (short)f2bf(v[i] + bb);
          *(short4v*)vrow = pq;
        }
      } else {
        const float bb = b0[col];
#pragma unroll
        for (int i = 0; i < 4; i++) {
          const size_t idx = (size_t)(row0 + i) * N + col;
          of[idx] = v[i] + bb + resid[idx];
        }
      }
    }
  }
}

// ---------------- gemm_p3: 3-slot counted-vmcnt pipeline (U, D) --------------
// BK=32, 3 LDS slots (48KB -> 3 blocks/CU), prefetch distance 2. Per iter:
//   stage(t+2) -> ds_read slot t%3 (compiler-scheduled lgkm waits) -> MFMA
//   -> vmcnt(4) [retire exactly tile t+1's 4 loads; t+2's stay in flight]
//   -> ONE barrier. Tail: vmcnt(0) once. Loads get ~2 iterations of flight.
// MODE: 4=U(bias+gelu,bf16) 5=D(bias+accum,f32)
template<int MODE, int N, int K, int STRIPE_N>
__global__ void __launch_bounds__(256) gemm_p3(
    const u16* __restrict__ A, const u16* __restrict__ Bt,
    const float* __restrict__ b0,
    u16* __restrict__ o0, float* __restrict__ of)
{
  __shared__ u16 As[3][128 * 32];
  __shared__ u16 Bs[3][128 * 32];
  constexpr int TN = N / 128;
  constexpr int NT = K / 32;

  const int bid = blockIdx.x;
  const int xcd = bid & 7, wl = bid >> 3;
  int m0, n0;
  if constexpr (STRIPE_N) {
    constexpr int NSTR = TN / 8;
    n0 = (xcd * NSTR + (wl % NSTR)) * 128;
    m0 = (wl / NSTR) * 128;
  } else {
    m0 = (xcd * 4 + (wl & 3)) * 128;
    n0 = (wl >> 2) * 128;
  }
  const int tid = threadIdx.x;
  const int lane = tid & 63, w = tid >> 6;
  const int wm = w >> 1, wn = w & 1;
  const int z = lane >> 4, l15 = lane & 15;

  f32x4 acc[4][4];
#pragma unroll
  for (int m = 0; m < 4; m++)
#pragma unroll
    for (int n = 0; n < 4; n++)
#pragma unroll
      for (int i = 0; i < 4; i++) acc[m][n][i] = 0.f;

  auto stage = [&](int g) {          // 4 loads/thread: 2 A + 2 B (32 K-cols)
    const int sl = g % 3;
    const int kc = g * 32;
#pragma unroll
    for (int s = 0; s < 2; s++) {
      const int c = s * 256 + tid;
      const int r = c >> 2, q = c & 3;
      const int cg = q ^ ((r >> 1) & 3);          // source pre-swizzle
      gload16(A + (size_t)(m0 + r) * K + kc + cg * 8, &As[sl][c * 8]);
    }
#pragma unroll
    for (int s = 0; s < 2; s++) {
      const int c = s * 256 + tid;
      const int r = c >> 2, q = c & 3;
      const int cg = q ^ ((r >> 1) & 3);
      gload16(Bt + (size_t)(n0 + r) * K + kc + cg * 8, &Bs[sl][c * 8]);
    }
  };

  stage(0); stage(1);
  asm volatile("s_waitcnt vmcnt(4)" ::: "memory");   // tile 0 resident
  __syncthreads();

  for (int t = 0; t < NT; t++) {
    const int sl = t % 3;
    if (t + 2 < NT) stage(t + 2);

    short8 af[4], bfr[4];
#pragma unroll
    for (int m = 0; m < 4; m++) {
      const int row = wm * 64 + m * 16 + l15;
      af[m] = *(const short8*)&As[sl][row * 32 + ((z ^ ((row >> 1) & 3)) * 8)];
    }
#pragma unroll
    for (int n = 0; n < 4; n++) {
      const int row = wn * 64 + n * 16 + l15;
      bfr[n] = *(const short8*)&Bs[sl][row * 32 + ((z ^ ((row >> 1) & 3)) * 8)];
    }
    __builtin_amdgcn_s_setprio(1);
#pragma unroll
    for (int m = 0; m < 4; m++)
#pragma unroll
      for (int n = 0; n < 4; n++)
        acc[m][n] = mfma_bf16(af[m], bfr[n], acc[m][n]);
    __builtin_amdgcn_s_setprio(0);

    if (t + 2 < NT) {
      asm volatile("s_waitcnt vmcnt(4)" ::: "memory");  // retire tile t+1 only
      __syncthreads();
    } else if (t + 1 < NT) {
      asm volatile("s_waitcnt vmcnt(0)" ::: "memory");  // drain last tile
      __syncthreads();
    }
  }

#pragma unroll
  for (int m = 0; m < 4; m++) {
    const int row0 = m0 + wm * 64 + m * 16 + z * 4;
#pragma unroll
    for (int n = 0; n < 4; n++) {
      const int col = n0 + wn * 64 + n * 16 + l15;
      f32x4 v = acc[m][n];
      const float bb = b0[col];
      if constexpr (MODE == 4) {
#pragma unroll
        for (int i = 0; i < 4; i++) {
          const float xx = v[i] + bb;
          o0[(size_t)(row0 + i) * N + col] =
              f2bf(0.5f * xx * (1.f + erff(xx * 0.70710678118654752f)));
        }
      } else {
#pragma unroll
        for (int i = 0; i < 4; i++) {
          const size_t idx = (size_t)(row0 + i) * N + col;
          of[idx] = v[i] + bb + of[idx];
        }
      }
    }
  }
}

// ---------------- Flash attention, causal, GQA. 128 q-rows/block, 4 waves -----
__global__ void __launch_bounds__(256) attn_kernel(
    const u16* __restrict__ qb, const u16* __restrict__ kb,
    const u16* __restrict__ vt, u16* __restrict__ ob)
{
  __shared__ u16 Kt[2][64 * 128];
  __shared__ u16 Vs[2][128 * 64];
  __shared__ u16 Pl[4 * 32 * 64];

  const int idx = blockIdx.x;
  const int xcd = idx & 7;
  const int u = (idx >> 3) & 31;
  const int half = idx >> 8;
  const int bh = xcd * 4 + (u & 3);
  const int qh = u >> 2;
  const int qt = half ? (15 - qh) : qh;

  const int b = bh >> 4, h = bh & 15, kh = h >> 2;
  const int q0 = qt * 128;
  const int tid = threadIdx.x, lane = tid & 63, w = tid >> 6;
  const int z = lane >> 4, l15 = lane & 15;
  const int qw0 = q0 + w * 32;
  const int ksw = (l15 & 7) << 3;

  short8 qf[2][4];
#pragma unroll
  for (int m = 0; m < 2; m++)
#pragma unroll
    for (int kk = 0; kk < 4; kk++)
      qf[m][kk] = *(const short8*)&qb[(size_t)(b * 2048 + qw0 + m * 16 + l15) * 2048 +
                                      h * 128 + kk * 32 + z * 8];

  f32x4 oacc[2][8];
#pragma unroll
  for (int m = 0; m < 2; m++)
#pragma unroll
    for (int n = 0; n < 8; n++)
#pragma unroll
      for (int i = 0; i < 4; i++) oacc[m][n][i] = 0.f;
  float mst[2][4], lst[2][4];
#pragma unroll
  for (int m = 0; m < 2; m++)
#pragma unroll
    for (int i = 0; i < 4; i++) { mst[m][i] = -1e30f; lst[m][i] = 0.f; }

  auto STAGE = [&](int tt, int bufsel) {
    const int kv0s = tt * 64;
#pragma unroll
    for (int j = 0; j < 4; j++) {
      const int seg = w * 4 + j;
      const int c = seg * 64 + lane;
      const int r = c >> 4;
      const int cc = (c & 15) ^ (r & 7);
      gload16(kb + (size_t)(b * 2048 + kv0s + r) * 512 + kh * 128 + cc * 8,
              &Kt[bufsel][seg * 512]);
    }
#pragma unroll
    for (int j = 0; j < 4; j++) {
      const int seg = w * 4 + j;
      const int c = seg * 64 + lane;
      const int d = c >> 3;
      const int cc = (c & 7) ^ (d & 7);
      gload16(vt + (size_t)((b * 4 + kh) * 128 + d) * 2048 + kv0s + cc * 8,
              &Vs[bufsel][seg * 512]);
    }
  };

  const int ntiles = q0 / 64 + 2;

  STAGE(0, 0);
  asm volatile("s_waitcnt vmcnt(0)" ::: "memory");
  __syncthreads();

  for (int t = 0; t < ntiles; t++) {
    const int cur = t & 1;
    if (t + 1 < ntiles) STAGE(t + 1, cur ^ 1);

    const int kv0 = t * 64;
    if (kv0 <= qw0 + 31) {
      f32x4 sf[2][4];
#pragma unroll
      for (int m = 0; m < 2; m++)
#pragma unroll
        for (int n = 0; n < 4; n++)
#pragma unroll
          for (int i = 0; i < 4; i++) sf[m][n][i] = 0.f;

      __builtin_amdgcn_s_setprio(1);
#pragma unroll
      for (int kk = 0; kk < 4; kk++) {
        short8 kfr[4];
#pragma unroll
        for (int n = 0; n < 4; n++) {
          const int row = n * 16 + l15;
          kfr[n] = *(const short8*)&Kt[cur][row * 128 + ((kk * 32 + z * 8) ^ ksw)];
        }
#pragma unroll
        for (int m = 0; m < 2; m++)
#pragma unroll
          for (int n = 0; n < 4; n++)
            sf[m][n] = mfma_bf16(qf[m][kk], kfr[n], sf[m][n]);
      }
      __builtin_amdgcn_s_setprio(0);

      u16* Pw = &Pl[w * 2048];
      const bool edge = (kv0 + 63 > qw0);
#pragma unroll
      for (int m = 0; m < 2; m++) {
#pragma unroll
        for (int i = 0; i < 4; i++) {
          const int rq = qw0 + m * 16 + z * 4 + i;
          if (edge) {
#pragma unroll
            for (int n = 0; n < 4; n++)
              if (kv0 + n * 16 + l15 > rq) sf[m][n][i] = -1e30f;
          }
          float mx = fmaxf(fmaxf(sf[m][0][i], sf[m][1][i]), fmaxf(sf[m][2][i], sf[m][3][i]));
          mx = fmaxf(mx, __shfl_xor(mx, 1));
          mx = fmaxf(mx, __shfl_xor(mx, 2));
          mx = fmaxf(mx, __shfl_xor(mx, 4));
          mx = fmaxf(mx, __shfl_xor(mx, 8));
          const bool grow = mx > mst[m][i];
          const float mn = grow ? mx : mst[m][i];
          float rs = 0.f;
#pragma unroll
          for (int n = 0; n < 4; n++) {
            const float p = __expf(sf[m][n][i] - mn);
            sf[m][n][i] = p;
            rs += p;
          }
          rs += __shfl_xor(rs, 1);
          rs += __shfl_xor(rs, 2);
          rs += __shfl_xor(rs, 4);
          rs += __shfl_xor(rs, 8);
          if (grow) {
            const float al = __expf(mst[m][i] - mx);
            mst[m][i] = mx;
            lst[m][i] = lst[m][i] * al + rs;
#pragma unroll
            for (int n = 0; n < 8; n++) oacc[m][n][i] *= al;
          } else {
            lst[m][i] += rs;
          }
          const int prow = m * 16 + z * 4 + i;
          const int psw = ((z * 4 + i) & 7) << 3;
#pragma unroll
          for (int n = 0; n < 4; n++)
            Pw[prow * 64 + ((n * 16 + l15) ^ psw)] = f2bf(sf[m][n][i]);
        }
      }

      __builtin_amdgcn_s_setprio(1);
#pragma unroll
      for (int kk = 0; kk < 2; kk++) {
        short8 af[2], vf[8];
#pragma unroll
        for (int m = 0; m < 2; m++) {
          const int row = m * 16 + l15;
          af[m] = *(const short8*)&Pw[row * 64 + ((kk * 32 + z * 8) ^ ksw)];
        }
#pragma unroll
        for (int n = 0; n < 8; n++) {
          const int row = n * 16 + l15;
          vf[n] = *(const short8*)&Vs[cur][row * 64 + ((kk * 32 + z * 8) ^ ksw)];
        }
#pragma unroll
        for (int m = 0; m < 2; m++)
#pragma unroll
          for (int n = 0; n < 8; n++)
            oacc[m][n] = mfma_bf16(af[m], vf[n], oacc[m][n]);
      }
      __builtin_amdgcn_s_setprio(0);
    }

    asm volatile("s_waitcnt vmcnt(0)" ::: "memory");
    __syncthreads();
  }

#pragma unroll
  for (int m = 0; m < 2; m++)
#pragma unroll
    for (int i = 0; i < 4; i++) {
      const float inv = 1.0f / lst[m][i];
      const int rq = qw0 + m * 16 + z * 4 + i;
      u16* orow = &ob[(size_t)(b * 2048 + rq) * 2048 + h * 128];
#pragma unroll
      for (int n = 0; n < 8; n++)
        orow[n * 16 + l15] = f2bf(oacc[m][n][i] * inv);
    }
}

// ------------------------------------------------------------------------------
extern "C" void kernel_launch(void* const* d_in, const int* in_sizes, int n_in,
                              void* d_out, int out_size, void* d_ws, size_t ws_size,
                              hipStream_t stream) {
  (void)in_sizes; (void)n_in; (void)out_size; (void)ws_size;
  const float* x     = (const float*)d_in[0];
  const float* ln1_g = (const float*)d_in[1];
  const float* ln1_b = (const float*)d_in[2];
  const float* wq    = (const float*)d_in[3];
  const float* bq    = (const float*)d_in[4];
  const float* wk    = (const float*)d_in[5];
  const float* bk    = (const float*)d_in[6];
  const float* wv    = (const float*)d_in[7];
  const float* bv    = (const float*)d_in[8];
  const float* wo    = (const float*)d_in[9];
  const float* bo    = (const float*)d_in[10];
  const float* ln2_g = (const float*)d_in[11];
  const float* ln2_b = (const float*)d_in[12];
  const float* wu    = (const float*)d_in[13];
  const float* bu    = (const float*)d_in[14];
  const float* wd    = (const float*)d_in[15];
  const float* bd    = (const float*)d_in[16];
  float* out = (float*)d_out;

  char* p = (char*)d_ws;
  u16* wqT = (u16*)p; p += (size_t)2048 * 2048 * 2;   // wq^T | wk^T | wv^T contiguous
  u16* wkT = (u16*)p; p += (size_t)512 * 2048 * 2;
  u16* wvT = (u16*)p; p += (size_t)512 * 2048 * 2;
  u16* woT = (u16*)p; p += (size_t)2048 * 2048 * 2;
  u16* wuT = (u16*)p; p += (size_t)8192 * 2048 * 2;
  u16* wdT = (u16*)p; p += (size_t)2048 * 8192 * 2;
  u16* x1  = (u16*)p; p += (size_t)4096 * 2048 * 2;   // reused as attention output
  u16* qbuf= (u16*)p; p += (size_t)4096 * 2048 * 2;   // reused as x2 (post-LN2)
  u16* kbuf= (u16*)p; p += (size_t)4096 * 512 * 2;
  u16* vtb = (u16*)p; p += (size_t)4096 * 512 * 2;    // V^T layout [b][kh][d][s]
  u16* hb  = (u16*)p; p += (size_t)4096 * 8192 * 2;
  u16* ob  = x1;
  u16* x2  = qbuf;

  // LN1 + all weight transposes in one launch
  prep_kernel<<<47104, 256, 0, stream>>>(
      x, ln1_g, ln1_b, x1, wq, wk, wv, wo, wu, wd,
      wqT, wkT, wvT, woT, wuT, wdT);

  // fused QKV: B = [wq|wk|wv]^T (3072x2048)
  gemm_sb<6, 3072, 2048, 0><<<768, 256, 0, stream>>>(
      x1, wqT, bq, bk, bv, nullptr, qbuf, kbuf, vtb, nullptr);

  attn_kernel<<<512, 256, 0, stream>>>(qbuf, kbuf, vtb, ob);

  gemm_sb<3, 2048, 2048, 0><<<512, 256, 0, stream>>>(
      ob, woT, bo, nullptr, nullptr, x, nullptr, nullptr, nullptr, out);

  ln_kernel<<<4096, 256, 0, stream>>>(out, ln2_g, ln2_b, x2);

  // U and D: 3-slot counted-vmcnt pipeline
  gemm_p3<4, 8192, 2048, 1><<<2048, 256, 0, stream>>>(x2, wuT, bu, hb, nullptr);
  gemm_p3<5, 2048, 8192, 1><<<512, 256, 0, stream>>>(hb, wdT, bd, nullptr, out);
}

// Round 12
// 712.631 us; speedup vs baseline: 1.0889x; 1.0889x over previous
//
#include <hip/hip_runtime.h>
#include <hip/hip_bf16.h>
#include <cstdint>
#include <math.h>

// Problem constants: B=2,S=2048,E=2048,H=16,KH=4,G=4,D=128,F=8192, M=B*S=4096
typedef unsigned short u16;
using f32x4   = __attribute__((ext_vector_type(4))) float;
using short8  = __attribute__((ext_vector_type(8))) short;
using short4v = __attribute__((ext_vector_type(4))) short;

#define DEV static __device__ __forceinline__

DEV u16 f2bf(float f) {  // RNE f32 -> bf16
  union { float f; unsigned u; } v; v.f = f;
  unsigned r = v.u + 0x7fffu + ((v.u >> 16) & 1u);
  return (u16)(r >> 16);
}

DEV f32x4 mfma_bf16(short8 a, short8 b, f32x4 c) {
  return __builtin_amdgcn_mfma_f32_16x16x32_bf16(a, b, c, 0, 0, 0);
}

DEV void gload16(const void* g, void* l) {  // async global->LDS, 16B/lane, LDS base wave-uniform
  __builtin_amdgcn_global_load_lds((const __attribute__((address_space(1))) void*)g,
                                   (__attribute__((address_space(3))) void*)l,
                                   16, 0, 0);
}

// ---------------- prep mega-kernel: LN1 + all 6 weight transposes ------------
__global__ __launch_bounds__(256) void prep_kernel(
    const float* __restrict__ x, const float* __restrict__ g,
    const float* __restrict__ bt, u16* __restrict__ x1,
    const float* __restrict__ wq, const float* __restrict__ wk,
    const float* __restrict__ wv, const float* __restrict__ wo,
    const float* __restrict__ wu, const float* __restrict__ wd,
    u16* __restrict__ wqT, u16* __restrict__ wkT, u16* __restrict__ wvT,
    u16* __restrict__ woT, u16* __restrict__ wuT, u16* __restrict__ wdT)
{
  __shared__ float sm[32 * 33];
  int bid = blockIdx.x;
  const int t = threadIdx.x;

  if (bid < 4096) {                                    // ---- LayerNorm 1 ----
    const int lane = t & 63, w = t >> 6;
    const float* xr = x + (size_t)bid * 2048 + t * 8;
    float v[8];
    {
      const float4* p4 = (const float4*)xr;
      float4 a = p4[0], b = p4[1];
      v[0] = a.x; v[1] = a.y; v[2] = a.z; v[3] = a.w;
      v[4] = b.x; v[5] = b.y; v[6] = b.z; v[7] = b.w;
    }
    float s = 0.f;
#pragma unroll
    for (int j = 0; j < 8; j++) s += v[j];
#pragma unroll
    for (int m = 1; m < 64; m <<= 1) s += __shfl_xor(s, m);
    if (lane == 0) sm[w] = s;
    __syncthreads();
    const float mu = (sm[0] + sm[1] + sm[2] + sm[3]) * (1.f / 2048.f);
    float q = 0.f;
#pragma unroll
    for (int j = 0; j < 8; j++) { v[j] -= mu; q += v[j] * v[j]; }
#pragma unroll
    for (int m = 1; m < 64; m <<= 1) q += __shfl_xor(q, m);
    if (lane == 0) sm[4 + w] = q;
    __syncthreads();
    const float rstd = rsqrtf((sm[4] + sm[5] + sm[6] + sm[7]) * (1.f / 2048.f) + 1e-5f);
    const float4* g4 = (const float4*)(g + t * 8);
    const float4* b4 = (const float4*)(bt + t * 8);
    float4 ga = g4[0], gb = g4[1], ba = b4[0], bb = b4[1];
    float gg[8] = {ga.x, ga.y, ga.z, ga.w, gb.x, gb.y, gb.z, gb.w};
    float bbv[8] = {ba.x, ba.y, ba.z, ba.w, bb.x, bb.y, bb.z, bb.w};
    short8 o;
#pragma unroll
    for (int j = 0; j < 8; j++) o[j] = (short)f2bf(v[j] * rstd * gg[j] + bbv[j]);
    *(short8*)&x1[(size_t)bid * 2048 + t * 8] = o;
    return;
  }
  bid -= 4096;

  const float* in; u16* outp; int K, N, bx, by;
  if (bid < 4096)              { in = wq; outp = wqT; K = 2048; N = 2048; bx = bid & 63;  by = bid >> 6; }
  else if ((bid -= 4096) < 1024)  { in = wk; outp = wkT; K = 2048; N = 512;  bx = bid & 15;  by = bid >> 4; }
  else if ((bid -= 1024) < 1024)  { in = wv; outp = wvT; K = 2048; N = 512;  bx = bid & 15;  by = bid >> 4; }
  else if ((bid -= 1024) < 4096)  { in = wo; outp = woT; K = 2048; N = 2048; bx = bid & 63;  by = bid >> 6; }
  else if ((bid -= 4096) < 16384) { in = wu; outp = wuT; K = 2048; N = 8192; bx = bid & 255; by = bid >> 8; }
  else { bid -= 16384;            in = wd; outp = wdT; K = 8192; N = 2048; bx = bid & 63;  by = bid >> 6; }

  const int n0 = bx * 32, k0 = by * 32;
  {
    const int c = t & 31, r = t >> 5;               // r in 0..7
#pragma unroll
    for (int i = 0; i < 4; i++)
      sm[(r + i * 8) * 33 + c] = in[(size_t)(k0 + r + i * 8) * N + n0 + c];
  }
  __syncthreads();
  {
    const int c4 = (t & 7) * 4, r = t >> 3;         // r in 0..31
    short4v o;
#pragma unroll
    for (int j = 0; j < 4; j++) o[j] = (short)f2bf(sm[(c4 + j) * 33 + r]);
    *(short4v*)&outp[(size_t)(n0 + r) * K + k0 + c4] = o;
  }
}

// ---------------- LayerNorm (f32 in, bf16 out), one row (2048) per block ------
__global__ __launch_bounds__(256) void ln_kernel(
    const float* __restrict__ x, const float* __restrict__ g,
    const float* __restrict__ bt, u16* __restrict__ out)
{
  __shared__ float red1[4], red2[4];
  const int row = blockIdx.x;
  const int t = threadIdx.x;
  const int lane = t & 63, w = t >> 6;
  const float* xr = x + (size_t)row * 2048 + t * 8;
  float v[8];
  {
    const float4* p4 = (const float4*)xr;
    float4 a = p4[0], b = p4[1];
    v[0] = a.x; v[1] = a.y; v[2] = a.z; v[3] = a.w;
    v[4] = b.x; v[5] = b.y; v[6] = b.z; v[7] = b.w;
  }
  float s = 0.f;
#pragma unroll
  for (int j = 0; j < 8; j++) s += v[j];
#pragma unroll
  for (int m = 1; m < 64; m <<= 1) s += __shfl_xor(s, m);
  if (lane == 0) red1[w] = s;
  __syncthreads();
  const float mu = (red1[0] + red1[1] + red1[2] + red1[3]) * (1.f / 2048.f);
  float q = 0.f;
#pragma unroll
  for (int j = 0; j < 8; j++) { v[j] -= mu; q += v[j] * v[j]; }
#pragma unroll
  for (int m = 1; m < 64; m <<= 1) q += __shfl_xor(q, m);
  if (lane == 0) red2[w] = q;
  __syncthreads();
  const float rstd = rsqrtf((red2[0] + red2[1] + red2[2] + red2[3]) * (1.f / 2048.f) + 1e-5f);
  const float4* g4 = (const float4*)(g + t * 8);
  const float4* b4 = (const float4*)(bt + t * 8);
  float4 ga = g4[0], gb = g4[1], ba = b4[0], bb = b4[1];
  float gg[8] = {ga.x, ga.y, ga.z, ga.w, gb.x, gb.y, gb.z, gb.w};
  float bbv[8] = {ba.x, ba.y, ba.z, ba.w, bb.x, bb.y, bb.z, bb.w};
  short8 o;
#pragma unroll
  for (int j = 0; j < 8; j++) o[j] = (short)f2bf(v[j] * rstd * gg[j] + bbv[j]);
  *(short8*)&out[(size_t)row * 2048 + t * 8] = o;
}

// ---------------- gemm_sb: single-buffered m97 structure (QKV, O) ------------
// 32KB LDS, 2 barriers/K-tile; best measured for the short-K (K=2048) GEMMs.
// MODE: 3=O(bias+resid,f32) 6=QKV fused
template<int MODE, int N, int K, int STRIPE_N>
__global__ void __launch_bounds__(256) gemm_sb(
    const u16* __restrict__ A, const u16* __restrict__ Bt,
    const float* __restrict__ b0, const float* __restrict__ b1,
    const float* __restrict__ b2, const float* __restrict__ resid,
    u16* __restrict__ o0, u16* __restrict__ o1, u16* __restrict__ o2,
    float* __restrict__ of)
{
  __shared__ u16 As[128 * 64];
  __shared__ u16 Bs[128 * 64];
  constexpr int TN = N / 128;

  const int bid = blockIdx.x;
  const int xcd = bid & 7, wl = bid >> 3;
  int m0, n0;
  if constexpr (STRIPE_N) {
    constexpr int NSTR = TN / 8;
    n0 = (xcd * NSTR + (wl % NSTR)) * 128;
    m0 = (wl / NSTR) * 128;
  } else {
    m0 = (xcd * 4 + (wl & 3)) * 128;
    n0 = (wl >> 2) * 128;
  }
  const int tid = threadIdx.x;
  const int lane = tid & 63, w = tid >> 6;
  const int wm = w >> 1, wn = w & 1;
  const int z = lane >> 4, l15 = lane & 15;

  f32x4 acc[4][4];
#pragma unroll
  for (int m = 0; m < 4; m++)
#pragma unroll
    for (int n = 0; n < 4; n++)
#pragma unroll
      for (int i = 0; i < 4; i++) acc[m][n][i] = 0.f;

  for (int k0 = 0; k0 < K; k0 += 64) {
#pragma unroll
    for (int j = 0; j < 4; j++) {
      const int seg = w * 4 + j;
      const int c = seg * 64 + lane;
      const int r = c >> 3;
      const int cc = (c & 7) ^ (r & 7);
      gload16(A + (size_t)(m0 + r) * K + k0 + cc * 8, &As[seg * 512]);
    }
#pragma unroll
    for (int j = 0; j < 4; j++) {
      const int seg = w * 4 + j;
      const int c = seg * 64 + lane;
      const int r = c >> 3;
      const int cc = (c & 7) ^ (r & 7);
      gload16(Bt + (size_t)(n0 + r) * K + k0 + cc * 8, &Bs[seg * 512]);
    }
    asm volatile("s_waitcnt vmcnt(0)" ::: "memory");
    __syncthreads();

#pragma unroll
    for (int kk = 0; kk < 2; kk++) {
      short8 af[4], bfr[4];
#pragma unroll
      for (int m = 0; m < 4; m++) {
        const int row = wm * 64 + m * 16 + l15;
        const int off = row * 64 + ((kk * 32 + z * 8) ^ ((row & 7) << 3));
        af[m] = *(const short8*)&As[off];
      }
#pragma unroll
      for (int n = 0; n < 4; n++) {
        const int row = wn * 64 + n * 16 + l15;
        const int off = row * 64 + ((kk * 32 + z * 8) ^ ((row & 7) << 3));
        bfr[n] = *(const short8*)&Bs[off];
      }
      __builtin_amdgcn_s_setprio(1);
#pragma unroll
      for (int m = 0; m < 4; m++)
#pragma unroll
        for (int n = 0; n < 4; n++)
          acc[m][n] = mfma_bf16(af[m], bfr[n], acc[m][n]);
      __builtin_amdgcn_s_setprio(0);
    }
    __syncthreads();
  }

#pragma unroll
  for (int m = 0; m < 4; m++) {
    const int row0 = m0 + wm * 64 + m * 16 + z * 4;
#pragma unroll
    for (int n = 0; n < 4; n++) {
      const int col = n0 + wn * 64 + n * 16 + l15;
      f32x4 v = acc[m][n];
      if constexpr (MODE == 6) {
        if (col < 2048) {
          const float bb = b0[col];
#pragma unroll
          for (int i = 0; i < 4; i++)
            o0[(size_t)(row0 + i) * 2048 + col] = f2bf((v[i] + bb) * 0.08838834764831845f);
        } else if (col < 2560) {
          const int ck = col - 2048;
          const float bb = b1[ck];
#pragma unroll
          for (int i = 0; i < 4; i++)
            o1[(size_t)(row0 + i) * 512 + ck] = f2bf(v[i] + bb);
        } else {
          const int cc = col - 2560;
          const float bb = b2[cc];
          const int kh = cc >> 7, d = cc & 127;
          const int bidx = row0 >> 11, sidx = row0 & 2047;
          u16* vrow = &o2[((size_t)(bidx * 4 + kh) * 128 + d) * 2048 + sidx];
          short4v pq;
#pragma unroll
          for (int i = 0; i < 4; i++) pq[i] = (short)f2bf(v[i] + bb);
          *(short4v*)vrow = pq;
        }
      } else {
        const float bb = b0[col];
#pragma unroll
        for (int i = 0; i < 4; i++) {
          const size_t idx = (size_t)(row0 + i) * N + col;
          of[idx] = v[i] + bb + resid[idx];
        }
      }
    }
  }
}

// ---------------- gemm_db: double-buffered, ONE barrier/K-tile (U, D) --------
// 64KB LDS; best measured for the long/wide GEMMs (194 us, FETCH ~131 MB).
// MODE: 4=U(bias+gelu,bf16) 5=D(bias+accum,f32)
template<int MODE, int N, int K, int STRIPE_N>
__global__ void __launch_bounds__(256) gemm_db(
    const u16* __restrict__ A, const u16* __restrict__ Bt,
    const float* __restrict__ b0,
    u16* __restrict__ o0, float* __restrict__ of)
{
  __shared__ u16 As[2][128 * 64];
  __shared__ u16 Bs[2][128 * 64];
  constexpr int TN = N / 128;
  constexpr int NT = K / 64;

  const int bid = blockIdx.x;
  const int xcd = bid & 7, wl = bid >> 3;
  int m0, n0;
  if constexpr (STRIPE_N) {
    constexpr int NSTR = TN / 8;
    n0 = (xcd * NSTR + (wl % NSTR)) * 128;
    m0 = (wl / NSTR) * 128;
  } else {
    m0 = (xcd * 4 + (wl & 3)) * 128;
    n0 = (wl >> 2) * 128;
  }
  const int tid = threadIdx.x;
  const int lane = tid & 63, w = tid >> 6;
  const int wm = w >> 1, wn = w & 1;
  const int z = lane >> 4, l15 = lane & 15;

  f32x4 acc[4][4];
#pragma unroll
  for (int m = 0; m < 4; m++)
#pragma unroll
    for (int n = 0; n < 4; n++)
#pragma unroll
      for (int i = 0; i < 4; i++) acc[m][n][i] = 0.f;

  auto stage = [&](int k0, int buf) {
#pragma unroll
    for (int j = 0; j < 4; j++) {
      const int seg = w * 4 + j;
      const int c = seg * 64 + lane;
      const int r = c >> 3;
      const int cc = (c & 7) ^ (r & 7);
      gload16(A + (size_t)(m0 + r) * K + k0 + cc * 8, &As[buf][seg * 512]);
    }
#pragma unroll
    for (int j = 0; j < 4; j++) {
      const int seg = w * 4 + j;
      const int c = seg * 64 + lane;
      const int r = c >> 3;
      const int cc = (c & 7) ^ (r & 7);
      gload16(Bt + (size_t)(n0 + r) * K + k0 + cc * 8, &Bs[buf][seg * 512]);
    }
  };

  stage(0, 0);
  asm volatile("s_waitcnt vmcnt(0)" ::: "memory");
  __syncthreads();

  int cur = 0;
  for (int t = 0; t < NT; t++) {
    if (t + 1 < NT) stage((t + 1) * 64, cur ^ 1);  // prefetch overlaps MFMA

#pragma unroll
    for (int kk = 0; kk < 2; kk++) {
      short8 af[4], bfr[4];
#pragma unroll
      for (int m = 0; m < 4; m++) {
        const int row = wm * 64 + m * 16 + l15;
        const int off = row * 64 + ((kk * 32 + z * 8) ^ ((row & 7) << 3));
        af[m] = *(const short8*)&As[cur][off];
      }
#pragma unroll
      for (int n = 0; n < 4; n++) {
        const int row = wn * 64 + n * 16 + l15;
        const int off = row * 64 + ((kk * 32 + z * 8) ^ ((row & 7) << 3));
        bfr[n] = *(const short8*)&Bs[cur][off];
      }
      __builtin_amdgcn_s_setprio(1);
#pragma unroll
      for (int m = 0; m < 4; m++)
#pragma unroll
        for (int n = 0; n < 4; n++)
          acc[m][n] = mfma_bf16(af[m], bfr[n], acc[m][n]);
      __builtin_amdgcn_s_setprio(0);
    }

    asm volatile("s_waitcnt vmcnt(0)" ::: "memory");
    __syncthreads();                               // ONE barrier per K-tile
    cur ^= 1;
  }

#pragma unroll
  for (int m = 0; m < 4; m++) {
    const int row0 = m0 + wm * 64 + m * 16 + z * 4;
#pragma unroll
    for (int n = 0; n < 4; n++) {
      const int col = n0 + wn * 64 + n * 16 + l15;
      f32x4 v = acc[m][n];
      const float bb = b0[col];
      if constexpr (MODE == 4) {
#pragma unroll
        for (int i = 0; i < 4; i++) {
          const float xx = v[i] + bb;
          o0[(size_t)(row0 + i) * N + col] =
              f2bf(0.5f * xx * (1.f + erff(xx * 0.70710678118654752f)));
        }
      } else {
#pragma unroll
        for (int i = 0; i < 4; i++) {
          const size_t idx = (size_t)(row0 + i) * N + col;
          of[idx] = v[i] + bb + of[idx];
        }
      }
    }
  }
}

// ---------------- Flash attention, causal, GQA. 128 q-rows/block, 4 waves -----
__global__ void __launch_bounds__(256) attn_kernel(
    const u16* __restrict__ qb, const u16* __restrict__ kb,
    const u16* __restrict__ vt, u16* __restrict__ ob)
{
  __shared__ u16 Kt[2][64 * 128];
  __shared__ u16 Vs[2][128 * 64];
  __shared__ u16 Pl[4 * 32 * 64];

  const int idx = blockIdx.x;
  const int xcd = idx & 7;
  const int u = (idx >> 3) & 31;
  const int half = idx >> 8;
  const int bh = xcd * 4 + (u & 3);
  const int qh = u >> 2;
  const int qt = half ? (15 - qh) : qh;

  const int b = bh >> 4, h = bh & 15, kh = h >> 2;
  const int q0 = qt * 128;
  const int tid = threadIdx.x, lane = tid & 63, w = tid >> 6;
  const int z = lane >> 4, l15 = lane & 15;
  const int qw0 = q0 + w * 32;
  const int ksw = (l15 & 7) << 3;

  short8 qf[2][4];
#pragma unroll
  for (int m = 0; m < 2; m++)
#pragma unroll
    for (int kk = 0; kk < 4; kk++)
      qf[m][kk] = *(const short8*)&qb[(size_t)(b * 2048 + qw0 + m * 16 + l15) * 2048 +
                                      h * 128 + kk * 32 + z * 8];

  f32x4 oacc[2][8];
#pragma unroll
  for (int m = 0; m < 2; m++)
#pragma unroll
    for (int n = 0; n < 8; n++)
#pragma unroll
      for (int i = 0; i < 4; i++) oacc[m][n][i] = 0.f;
  float mst[2][4], lst[2][4];
#pragma unroll
  for (int m = 0; m < 2; m++)
#pragma unroll
    for (int i = 0; i < 4; i++) { mst[m][i] = -1e30f; lst[m][i] = 0.f; }

  auto STAGE = [&](int tt, int bufsel) {
    const int kv0s = tt * 64;
#pragma unroll
    for (int j = 0; j < 4; j++) {
      const int seg = w * 4 + j;
      const int c = seg * 64 + lane;
      const int r = c >> 4;
      const int cc = (c & 15) ^ (r & 7);
      gload16(kb + (size_t)(b * 2048 + kv0s + r) * 512 + kh * 128 + cc * 8,
              &Kt[bufsel][seg * 512]);
    }
#pragma unroll
    for (int j = 0; j < 4; j++) {
      const int seg = w * 4 + j;
      const int c = seg * 64 + lane;
      const int d = c >> 3;
      const int cc = (c & 7) ^ (d & 7);
      gload16(vt + (size_t)((b * 4 + kh) * 128 + d) * 2048 + kv0s + cc * 8,
              &Vs[bufsel][seg * 512]);
    }
  };

  const int ntiles = q0 / 64 + 2;

  STAGE(0, 0);
  asm volatile("s_waitcnt vmcnt(0)" ::: "memory");
  __syncthreads();

  for (int t = 0; t < ntiles; t++) {
    const int cur = t & 1;
    if (t + 1 < ntiles) STAGE(t + 1, cur ^ 1);

    const int kv0 = t * 64;
    if (kv0 <= qw0 + 31) {
      f32x4 sf[2][4];
#pragma unroll
      for (int m = 0; m < 2; m++)
#pragma unroll
        for (int n = 0; n < 4; n++)
#pragma unroll
          for (int i = 0; i < 4; i++) sf[m][n][i] = 0.f;

      __builtin_amdgcn_s_setprio(1);
#pragma unroll
      for (int kk = 0; kk < 4; kk++) {
        short8 kfr[4];
#pragma unroll
        for (int n = 0; n < 4; n++) {
          const int row = n * 16 + l15;
          kfr[n] = *(const short8*)&Kt[cur][row * 128 + ((kk * 32 + z * 8) ^ ksw)];
        }
#pragma unroll
        for (int m = 0; m < 2; m++)
#pragma unroll
          for (int n = 0; n < 4; n++)
            sf[m][n] = mfma_bf16(qf[m][kk], kfr[n], sf[m][n]);
      }
      __builtin_amdgcn_s_setprio(0);

      u16* Pw = &Pl[w * 2048];
      const bool edge = (kv0 + 63 > qw0);
#pragma unroll
      for (int m = 0; m < 2; m++) {
#pragma unroll
        for (int i = 0; i < 4; i++) {
          const int rq = qw0 + m * 16 + z * 4 + i;
          if (edge) {
#pragma unroll
            for (int n = 0; n < 4; n++)
              if (kv0 + n * 16 + l15 > rq) sf[m][n][i] = -1e30f;
          }
          float mx = fmaxf(fmaxf(sf[m][0][i], sf[m][1][i]), fmaxf(sf[m][2][i], sf[m][3][i]));
          mx = fmaxf(mx, __shfl_xor(mx, 1));
          mx = fmaxf(mx, __shfl_xor(mx, 2));
          mx = fmaxf(mx, __shfl_xor(mx, 4));
          mx = fmaxf(mx, __shfl_xor(mx, 8));
          const bool grow = mx > mst[m][i];
          const float mn = grow ? mx : mst[m][i];
          float rs = 0.f;
#pragma unroll
          for (int n = 0; n < 4; n++) {
            const float p = __expf(sf[m][n][i] - mn);
            sf[m][n][i] = p;
            rs += p;
          }
          rs += __shfl_xor(rs, 1);
          rs += __shfl_xor(rs, 2);
          rs += __shfl_xor(rs, 4);
          rs += __shfl_xor(rs, 8);
          if (grow) {
            const float al = __expf(mst[m][i] - mx);
            mst[m][i] = mx;
            lst[m][i] = lst[m][i] * al + rs;
#pragma unroll
            for (int n = 0; n < 8; n++) oacc[m][n][i] *= al;
          } else {
            lst[m][i] += rs;
          }
          const int prow = m * 16 + z * 4 + i;
          const int psw = ((z * 4 + i) & 7) << 3;
#pragma unroll
          for (int n = 0; n < 4; n++)
            Pw[prow * 64 + ((n * 16 + l15) ^ psw)] = f2bf(sf[m][n][i]);
        }
      }

      __builtin_amdgcn_s_setprio(1);
#pragma unroll
      for (int kk = 0; kk < 2; kk++) {
        short8 af[2], vf[8];
#pragma unroll
        for (int m = 0; m < 2; m++) {
          const int row = m * 16 + l15;
          af[m] = *(const short8*)&Pw[row * 64 + ((kk * 32 + z * 8) ^ ksw)];
        }
#pragma unroll
        for (int n = 0; n < 8; n++) {
          const int row = n * 16 + l15;
          vf[n] = *(const short8*)&Vs[cur][row * 64 + ((kk * 32 + z * 8) ^ ksw)];
        }
#pragma unroll
        for (int m = 0; m < 2; m++)
#pragma unroll
          for (int n = 0; n < 8; n++)
            oacc[m][n] = mfma_bf16(af[m], vf[n], oacc[m][n]);
      }
      __builtin_amdgcn_s_setprio(0);
    }

    asm volatile("s_waitcnt vmcnt(0)" ::: "memory");
    __syncthreads();
  }

#pragma unroll
  for (int m = 0; m < 2; m++)
#pragma unroll
    for (int i = 0; i < 4; i++) {
      const float inv = 1.0f / lst[m][i];
      const int rq = qw0 + m * 16 + z * 4 + i;
      u16* orow = &ob[(size_t)(b * 2048 + rq) * 2048 + h * 128];
#pragma unroll
      for (int n = 0; n < 8; n++)
        orow[n * 16 + l15] = f2bf(oacc[m][n][i] * inv);
    }
}

// ------------------------------------------------------------------------------
extern "C" void kernel_launch(void* const* d_in, const int* in_sizes, int n_in,
                              void* d_out, int out_size, void* d_ws, size_t ws_size,
                              hipStream_t stream) {
  (void)in_sizes; (void)n_in; (void)out_size; (void)ws_size;
  const float* x     = (const float*)d_in[0];
  const float* ln1_g = (const float*)d_in[1];
  const float* ln1_b = (const float*)d_in[2];
  const float* wq    = (const float*)d_in[3];
  const float* bq    = (const float*)d_in[4];
  const float* wk    = (const float*)d_in[5];
  const float* bk    = (const float*)d_in[6];
  const float* wv    = (const float*)d_in[7];
  const float* bv    = (const float*)d_in[8];
  const float* wo    = (const float*)d_in[9];
  const float* bo    = (const float*)d_in[10];
  const float* ln2_g = (const float*)d_in[11];
  const float* ln2_b = (const float*)d_in[12];
  const float* wu    = (const float*)d_in[13];
  const float* bu    = (const float*)d_in[14];
  const float* wd    = (const float*)d_in[15];
  const float* bd    = (const float*)d_in[16];
  float* out = (float*)d_out;

  char* p = (char*)d_ws;
  u16* wqT = (u16*)p; p += (size_t)2048 * 2048 * 2;   // wq^T | wk^T | wv^T contiguous
  u16* wkT = (u16*)p; p += (size_t)512 * 2048 * 2;
  u16* wvT = (u16*)p; p += (size_t)512 * 2048 * 2;
  u16* woT = (u16*)p; p += (size_t)2048 * 2048 * 2;
  u16* wuT = (u16*)p; p += (size_t)8192 * 2048 * 2;
  u16* wdT = (u16*)p; p += (size_t)2048 * 8192 * 2;
  u16* x1  = (u16*)p; p += (size_t)4096 * 2048 * 2;   // reused as attention output
  u16* qbuf= (u16*)p; p += (size_t)4096 * 2048 * 2;   // reused as x2 (post-LN2)
  u16* kbuf= (u16*)p; p += (size_t)4096 * 512 * 2;
  u16* vtb = (u16*)p; p += (size_t)4096 * 512 * 2;    // V^T layout [b][kh][d][s]
  u16* hb  = (u16*)p; p += (size_t)4096 * 8192 * 2;
  u16* ob  = x1;
  u16* x2  = qbuf;

  // LN1 + all weight transposes in one launch
  prep_kernel<<<47104, 256, 0, stream>>>(
      x, ln1_g, ln1_b, x1, wq, wk, wv, wo, wu, wd,
      wqT, wkT, wvT, woT, wuT, wdT);

  // fused QKV: B = [wq|wk|wv]^T (3072x2048), single-buffered (best short-K)
  gemm_sb<6, 3072, 2048, 0><<<768, 256, 0, stream>>>(
      x1, wqT, bq, bk, bv, nullptr, qbuf, kbuf, vtb, nullptr);

  attn_kernel<<<512, 256, 0, stream>>>(qbuf, kbuf, vtb, ob);

  gemm_sb<3, 2048, 2048, 0><<<512, 256, 0, stream>>>(
      ob, woT, bo, nullptr, nullptr, x, nullptr, nullptr, nullptr, out);

  ln_kernel<<<4096, 256, 0, stream>>>(out, ln2_g, ln2_b, x2);

  // U and D: double-buffered, one barrier per K-tile (best measured: 194 us)
  gemm_db<4, 8192, 2048, 1><<<2048, 256, 0, stream>>>(x2, wuT, bu, hb, nullptr);
  gemm_db<5, 2048, 8192, 1><<<512, 256, 0, stream>>>(hb, wdT, bd, nullptr, out);
}